// Round 9
// baseline (345.783 us; speedup 1.0000x reference)
//
#include <hip/hip_runtime.h>
#include <hip/hip_bf16.h>

typedef __attribute__((ext_vector_type(4))) float f32x4;
typedef __attribute__((ext_vector_type(8))) short bf16x8;

#define DINF 1e30f

// ---------------------------------------------------------------------------
// round-to-nearest-even fp32 -> bf16 bits (inputs are finite gaussians)
__device__ __forceinline__ unsigned short f2bf(float f) {
    unsigned int u = __builtin_bit_cast(unsigned int, f);
    u += 0x7FFFu + ((u >> 16) & 1u);
    return (unsigned short)(u >> 16);
}

// ---------------------------------------------------------------------------
// Kernel 0: zero only the skew rows that contain parallelogram holes
// (rows 0..125 and 1024..1151; rows 126..1023 are fully GEMM-written).
__global__ __launch_bounds__(256) void zero_holes_kernel(float4* __restrict__ skew) {
    const int idx = blockIdx.x;       // 16 * 127 blocks; 2 rows per block
    const int bt  = idx / 127;
    const int pr  = idx % 127;
    const int h   = pr * 2 + (threadIdx.x >> 7);        // hole-row 0..253
    const int row = h < 126 ? h : 1024 + (h - 126);     // 0..125, 1024..1151
    const int c   = threadIdx.x & 127;                  // 128 x 16B = 2KB
    skew[((size_t)bt * 1152 + row) * 128 + c] = (float4){0.f, 0.f, 0.f, 0.f};
}

// ---------------------------------------------------------------------------
// Kernel 1: L2-normalize each 768-dim row, emit bf16.
__global__ __launch_bounds__(256) void norm_bf16_kernel(
    const float* __restrict__ s1, const float* __restrict__ s2,
    __hip_bfloat16* __restrict__ o1, __hip_bfloat16* __restrict__ o2) {
    const int gb = blockIdx.x;
    const float* in;
    __hip_bfloat16* out;
    int rowbase;
    if (gb < 4096) { in = s1; out = o1; rowbase = gb * 4; }
    else           { in = s2; out = o2; rowbase = (gb - 4096) * 4; }
    const int wv = threadIdx.x >> 6;
    const int l  = threadIdx.x & 63;
    const int row = rowbase + wv;

    const float* rp = in + (size_t)row * 768 + l * 4;
    float4 x0 = *(const float4*)(rp);
    float4 x1 = *(const float4*)(rp + 256);
    float4 x2 = *(const float4*)(rp + 512);

    float s = x0.x*x0.x + x0.y*x0.y + x0.z*x0.z + x0.w*x0.w
            + x1.x*x1.x + x1.y*x1.y + x1.z*x1.z + x1.w*x1.w
            + x2.x*x2.x + x2.y*x2.y + x2.z*x2.z + x2.w*x2.w;
#pragma unroll
    for (int off = 32; off > 0; off >>= 1) s += __shfl_xor(s, off, 64);

    const float inv = 1.0f / fmaxf(sqrtf(s), 1e-12f);

    __hip_bfloat16* op = out + (size_t)row * 768 + l * 4;
    ushort4 o;
    o.x = f2bf(x0.x*inv); o.y = f2bf(x0.y*inv); o.z = f2bf(x0.z*inv); o.w = f2bf(x0.w*inv);
    *(ushort4*)(op) = o;
    o.x = f2bf(x1.x*inv); o.y = f2bf(x1.y*inv); o.z = f2bf(x1.z*inv); o.w = f2bf(x1.w*inv);
    *(ushort4*)(op + 256) = o;
    o.x = f2bf(x2.x*inv); o.y = f2bf(x2.y*inv); o.z = f2bf(x2.z*inv); o.w = f2bf(x2.w*inv);
    *(ushort4*)(op + 512) = o;
}

// ---------------------------------------------------------------------------
// Kernel 2: GEMM -> SKEWED bf16 distance matrix (r7-proven).
// skew[b][row + 2*(col>>4)][col] = bf16(1 - dot(A[row], B[col])). 1152 rows.
#define GLOAD_LDS16(g, l)                                                      \
    __builtin_amdgcn_global_load_lds(                                          \
        (const __attribute__((address_space(1))) void*)(g),                    \
        (__attribute__((address_space(3))) void*)(l), 16, 0, 0)

__global__ __launch_bounds__(256) void gemm_dist_kernel(
    const __hip_bfloat16* __restrict__ A, const __hip_bfloat16* __restrict__ B,
    __hip_bfloat16* __restrict__ skew) {
    __shared__ __hip_bfloat16 lA[128 * 64];  // [row][k], rows of 128B
    __shared__ __hip_bfloat16 lB[128 * 64];

    const int blk  = (blockIdx.x & 7) * 128 + (blockIdx.x >> 3);
    const int b    = blk >> 6;
    const int tile = blk & 63;
    const int tm = tile >> 3, tn = tile & 7;
    const int tid  = threadIdx.x;
    const int lane = tid & 63, w = tid >> 6;
    const int lr = lane & 15, lg = lane >> 4;
    const int wm = w >> 1, wn = w & 1;

    const __hip_bfloat16* Ab = A + (size_t)b * (1024 * 768) + (size_t)(tm * 128) * 768;
    const __hip_bfloat16* Bb = B + (size_t)b * (1024 * 768) + (size_t)(tn * 128) * 768;

    const int srow = tid >> 3;        // 0..31 (row within 32-row chunk)
    const int scol = (tid & 7) * 8;   // k-octet (8 bf16 = 16B per lane)

    char* lAb = (char*)lA;
    char* lBb = (char*)lB;

    f32x4 acc[4][4];
#pragma unroll
    for (int m = 0; m < 4; ++m)
#pragma unroll
        for (int n = 0; n < 4; ++n) acc[m][n] = (f32x4){0.f, 0.f, 0.f, 0.f};

    for (int k0 = 0; k0 < 768; k0 += 64) {
#pragma unroll
        for (int q = 0; q < 4; ++q) {
            GLOAD_LDS16(Ab + (size_t)(q * 32 + srow) * 768 + k0 + scol,
                        lAb + q * 4096 + w * 1024);
            GLOAD_LDS16(Bb + (size_t)(q * 32 + srow) * 768 + k0 + scol,
                        lBb + q * 4096 + w * 1024);
        }
        __syncthreads();

#pragma unroll
        for (int ks = 0; ks < 64; ks += 32) {
            bf16x8 af[4], bfr[4];
#pragma unroll
            for (int m = 0; m < 4; ++m)
                af[m] = *(const bf16x8*)&lA[(wm * 64 + m * 16 + lr) * 64 + ks + lg * 8];
#pragma unroll
            for (int n = 0; n < 4; ++n)
                bfr[n] = *(const bf16x8*)&lB[(wn * 64 + n * 16 + lr) * 64 + ks + lg * 8];
#pragma unroll
            for (int m = 0; m < 4; ++m)
#pragma unroll
                for (int n = 0; n < 4; ++n)
                    acc[m][n] = __builtin_amdgcn_mfma_f32_16x16x32_bf16(af[m], bfr[n], acc[m][n], 0, 0, 0);
        }
        __syncthreads();
    }

    unsigned short* S = (unsigned short*)skew + (size_t)b * (1152 * 1024);
#pragma unroll
    for (int m = 0; m < 4; ++m)
#pragma unroll
        for (int n = 0; n < 4; ++n) {
            const int cb = tn * 128 + wn * 64 + n * 16;       // col base (mult of 16)
            const int soff = 2 * (cb >> 4);                   // skew offset for this col block
#pragma unroll
            for (int r = 0; r < 4; ++r) {
                const int row = tm * 128 + wm * 64 + m * 16 + lg * 4 + r;
                S[(size_t)(row + soff) * 1024 + cb + lr] = f2bf(1.0f - acc[m][n][r]);
            }
        }
}

// ---------------------------------------------------------------------------
// Kernel 3: DTW DP, TWO INDEPENDENT BATCHES PER WAVE (8 blocks x 64 lanes).
// Lane t owns cols [16t,16t+16) of both batch A (=2*blockIdx) and B (=+1).
// Each double-step executes A's step and B's step hand-interleaved, so B's
// independent chain links fill A's 4-cyc dependency stalls (r8 falsified
// issue-bound; r7/r8 measured ~360 cyc/step = issue + EXPOSED 128-cyc chain).
// Per-batch math is byte-identical to the r7-proven STEPB (skew-2, DINF
// flow). DMA ring: per-batch 2 banks x 8 rows (LDS = 2*2*8*2KB = 64KB);
// superbody j consumes bank[j&1] slots 2-7 (rolling X/Y), VWAIT(0) (next
// bank was issued a full superbody ~1500cyc ago -> free), reads next bank
// slots 0,1, then issues rows 8(j+2) into the just-drained bank[j&1].

#define VWAIT(n) asm volatile("s_waitcnt vmcnt(" #n ")" ::: "memory")

#define GLDMA16(g, l)                                                          \
    __builtin_amdgcn_global_load_lds(                                          \
        (const __attribute__((address_space(1))) void*)(g),                    \
        (__attribute__((address_space(3))) void*)(l), 16, 0, 0)

// skew row RW of batch BAT -> ring[BAT][BK][SL]; lane t's 32B (t*32 in Sb).
#define LOADR(BAT, BK, SL, RW) do {                                            \
    const char* g_ = Sb##BAT + ((size_t)(RW) << 11);                           \
    GLDMA16(g_,      &ring[BAT][BK][SL][0][0]);                                \
    GLDMA16(g_ + 16, &ring[BAT][BK][SL][1][0]);                                \
} while (0)

#define ISSUE16(BK, BASE) do {                                                 \
    LOADR(0, BK, 0, (BASE));     LOADR(1, BK, 0, (BASE));                      \
    LOADR(0, BK, 1, (BASE) + 1); LOADR(1, BK, 1, (BASE) + 1);                  \
    LOADR(0, BK, 2, (BASE) + 2); LOADR(1, BK, 2, (BASE) + 2);                  \
    LOADR(0, BK, 3, (BASE) + 3); LOADR(1, BK, 3, (BASE) + 3);                  \
    LOADR(0, BK, 4, (BASE) + 4); LOADR(1, BK, 4, (BASE) + 4);                  \
    LOADR(0, BK, 5, (BASE) + 5); LOADR(1, BK, 5, (BASE) + 5);                  \
    LOADR(0, BK, 6, (BASE) + 6); LOADR(1, BK, 6, (BASE) + 6);                  \
    LOADR(0, BK, 7, (BASE) + 7); LOADR(1, BK, 7, (BASE) + 7);                  \
} while (0)

// load both batches' lane-row into register buffers PA/PB
#define DSRD2(BK, SL, PA, PB) do {                                             \
    PA##_0 = ring[0][BK][SL][0][t]; PB##_0 = ring[1][BK][SL][0][t];            \
    PA##_1 = ring[0][BK][SL][1][t]; PB##_1 = ring[1][BK][SL][1][t];            \
} while (0)

#define BFLO(u) __builtin_bit_cast(float, (unsigned)((u) << 16))
#define BFHI(u) __builtin_bit_cast(float, (unsigned)((u) & 0xffff0000u))

// One double-step: batch A and batch B interleaved statement-by-statement.
#define STEPDUO(PA, PB, E0A, E0B) do {                                         \
    unsigned uA0_ = __builtin_bit_cast(unsigned, PA##_0.x);                    \
    unsigned uB0_ = __builtin_bit_cast(unsigned, PB##_0.x);                    \
    unsigned uA1_ = __builtin_bit_cast(unsigned, PA##_0.y);                    \
    unsigned uB1_ = __builtin_bit_cast(unsigned, PB##_0.y);                    \
    unsigned uA2_ = __builtin_bit_cast(unsigned, PA##_0.z);                    \
    unsigned uB2_ = __builtin_bit_cast(unsigned, PB##_0.z);                    \
    unsigned uA3_ = __builtin_bit_cast(unsigned, PA##_0.w);                    \
    unsigned uB3_ = __builtin_bit_cast(unsigned, PB##_0.w);                    \
    unsigned uA4_ = __builtin_bit_cast(unsigned, PA##_1.x);                    \
    unsigned uB4_ = __builtin_bit_cast(unsigned, PB##_1.x);                    \
    unsigned uA5_ = __builtin_bit_cast(unsigned, PA##_1.y);                    \
    unsigned uB5_ = __builtin_bit_cast(unsigned, PB##_1.y);                    \
    unsigned uA6_ = __builtin_bit_cast(unsigned, PA##_1.z);                    \
    unsigned uB6_ = __builtin_bit_cast(unsigned, PB##_1.z);                    \
    unsigned uA7_ = __builtin_bit_cast(unsigned, PA##_1.w);                    \
    unsigned uB7_ = __builtin_bit_cast(unsigned, PB##_1.w);                    \
    float eA_ = (E0A);                  float eB_ = (E0B);                     \
    float cA0_  = BFLO(uA0_) + eA_;                                            \
    float cB0_  = BFLO(uB0_) + eB_;                                            \
    float cA1_  = BFHI(uA0_) + fminf(fminf(pA1,  pA0),  cA0_);                 \
    float cB1_  = BFHI(uB0_) + fminf(fminf(pB1,  pB0),  cB0_);                 \
    float cA2_  = BFLO(uA1_) + fminf(fminf(pA2,  pA1),  cA1_);                 \
    float cB2_  = BFLO(uB1_) + fminf(fminf(pB2,  pB1),  cB1_);                 \
    float cA3_  = BFHI(uA1_) + fminf(fminf(pA3,  pA2),  cA2_);                 \
    float cB3_  = BFHI(uB1_) + fminf(fminf(pB3,  pB2),  cB2_);                 \
    float cA4_  = BFLO(uA2_) + fminf(fminf(pA4,  pA3),  cA3_);                 \
    float cB4_  = BFLO(uB2_) + fminf(fminf(pB4,  pB3),  cB3_);                 \
    float cA5_  = BFHI(uA2_) + fminf(fminf(pA5,  pA4),  cA4_);                 \
    float cB5_  = BFHI(uB2_) + fminf(fminf(pB5,  pB4),  cB4_);                 \
    float cA6_  = BFLO(uA3_) + fminf(fminf(pA6,  pA5),  cA5_);                 \
    float cB6_  = BFLO(uB3_) + fminf(fminf(pB6,  pB5),  cB5_);                 \
    float cA7_  = BFHI(uA3_) + fminf(fminf(pA7,  pA6),  cA6_);                 \
    float cB7_  = BFHI(uB3_) + fminf(fminf(pB7,  pB6),  cB6_);                 \
    float cA8_  = BFLO(uA4_) + fminf(fminf(pA8,  pA7),  cA7_);                 \
    float cB8_  = BFLO(uB4_) + fminf(fminf(pB8,  pB7),  cB7_);                 \
    float cA9_  = BFHI(uA4_) + fminf(fminf(pA9,  pA8),  cA8_);                 \
    float cB9_  = BFHI(uB4_) + fminf(fminf(pB9,  pB8),  cB8_);                 \
    float cA10_ = BFLO(uA5_) + fminf(fminf(pA10, pA9),  cA9_);                 \
    float cB10_ = BFLO(uB5_) + fminf(fminf(pB10, pB9),  cB9_);                 \
    float cA11_ = BFHI(uA5_) + fminf(fminf(pA11, pA10), cA10_);                \
    float cB11_ = BFHI(uB5_) + fminf(fminf(pB11, pB10), cB10_);                \
    float cA12_ = BFLO(uA6_) + fminf(fminf(pA12, pA11), cA11_);                \
    float cB12_ = BFLO(uB6_) + fminf(fminf(pB12, pB11), cB11_);                \
    float cA13_ = BFHI(uA6_) + fminf(fminf(pA13, pA12), cA12_);                \
    float cB13_ = BFHI(uB6_) + fminf(fminf(pB13, pB12), cB12_);                \
    float cA14_ = BFLO(uA7_) + fminf(fminf(pA14, pA13), cA13_);                \
    float cB14_ = BFLO(uB7_) + fminf(fminf(pB14, pB13), cB13_);                \
    float cA15_ = BFHI(uA7_) + fminf(fminf(pA15, pA14), cA14_);                \
    float cB15_ = BFHI(uB7_) + fminf(fminf(pB15, pB14), cB14_);                \
    pA0=cA0_; pA1=cA1_; pA2=cA2_; pA3=cA3_; pA4=cA4_; pA5=cA5_; pA6=cA6_;      \
    pA7=cA7_; pA8=cA8_; pA9=cA9_; pA10=cA10_; pA11=cA11_; pA12=cA12_;          \
    pA13=cA13_; pA14=cA14_; pA15=cA15_;                                        \
    pB0=cB0_; pB1=cB1_; pB2=cB2_; pB3=cB3_; pB4=cB4_; pB5=cB5_; pB6=cB6_;      \
    pB7=cB7_; pB8=cB8_; pB9=cB9_; pB10=cB10_; pB11=cB11_; pB12=cB12_;          \
    pB13=cB13_; pB14=cB14_; pB15=cB15_;                                        \
    a3A = a2A; a2A = a1A;                                                      \
    a3B = a2B; a2B = a1B;                                                      \
    a1A = __shfl_up(cA15_, 1, 64);                                             \
    a1B = __shfl_up(cB15_, 1, 64);                                             \
    a1A = lane0 ? DINF : a1A;                                                  \
    a1B = lane0 ? DINF : a1B;                                                  \
} while (0)

#define E0A_ fminf(fminf(pA0, a3A), a2A)
#define E0B_ fminf(fminf(pB0, a3B), a2B)
#define STEP2(PA, PB)       STEPDUO(PA, PB, E0A_, E0B_)
#define STEP2_FIRST(PA, PB) STEPDUO(PA, PB, lane0 ? 0.0f : E0A_, lane0 ? 0.0f : E0B_)

__global__ __launch_bounds__(64, 1) void dtw_dp_kernel(
    const __hip_bfloat16* __restrict__ skew, float* __restrict__ out) {
    __shared__ float4 ring[2][2][8][2][64];  // 64 KiB: [batch][bank][slot][chunk][lane]

    const int b0 = blockIdx.x * 2;
    const int t  = threadIdx.x;
    const bool lane0 = (t == 0);
    const char* Sb0 = (const char*)skew + (size_t)b0 * 2359296 + (t << 5);
    const char* Sb1 = Sb0 + 2359296;

    float pA0 = DINF, pA1 = DINF, pA2 = DINF, pA3 = DINF,
          pA4 = DINF, pA5 = DINF, pA6 = DINF, pA7 = DINF,
          pA8 = DINF, pA9 = DINF, pA10 = DINF, pA11 = DINF,
          pA12 = DINF, pA13 = DINF, pA14 = DINF, pA15 = DINF;
    float pB0 = DINF, pB1 = DINF, pB2 = DINF, pB3 = DINF,
          pB4 = DINF, pB5 = DINF, pB6 = DINF, pB7 = DINF,
          pB8 = DINF, pB9 = DINF, pB10 = DINF, pB11 = DINF,
          pB12 = DINF, pB13 = DINF, pB14 = DINF, pB15 = DINF;
    float a1A = DINF, a2A = DINF, a3A = DINF;
    float a1B = DINF, a2B = DINF, a3B = DINF;

    float4 XA_0, XA_1, XB_0, XB_1;   // even slots
    float4 YA_0, YA_1, YB_0, YB_1;   // odd slots

    // prologue: rows 0-7 -> bank 0, rows 8-15 -> bank 1 (64 DMA).
    ISSUE16(0, 0);
    ISSUE16(1, 8);
    VWAIT(32);                    // bank 0 (both batches) landed
    DSRD2(0, 0, XA, XB); DSRD2(0, 1, YA, YB);

    // superbody j=0 (steps 0..7): consume bank 0.
    STEP2_FIRST(XA, XB); DSRD2(0, 2, XA, XB);
    STEP2(YA, YB);       DSRD2(0, 3, YA, YB);
    STEP2(XA, XB);       DSRD2(0, 4, XA, XB);
    STEP2(YA, YB);       DSRD2(0, 5, YA, YB);
    STEP2(XA, XB);       DSRD2(0, 6, XA, XB);
    STEP2(YA, YB);       DSRD2(0, 7, YA, YB);
    VWAIT(0);                     // bank 1 landed
    STEP2(XA, XB);       DSRD2(1, 0, XA, XB);
    STEP2(YA, YB);       DSRD2(1, 1, YA, YB);
    ISSUE16(0, 16);               // rows 16-23 into drained bank 0

    // superbodies j=1..141 (steps 8..1135; last issues rows 1144-1151)
    int rb = 1, base = 24;
#pragma unroll 1
    for (int j = 1; j < 142; ++j) {
        const int nb = rb ^ 1;
        STEP2(XA, XB); DSRD2(rb, 2, XA, XB);
        STEP2(YA, YB); DSRD2(rb, 3, YA, YB);
        STEP2(XA, XB); DSRD2(rb, 4, XA, XB);
        STEP2(YA, YB); DSRD2(rb, 5, YA, YB);
        STEP2(XA, XB); DSRD2(rb, 6, XA, XB);
        STEP2(YA, YB); DSRD2(rb, 7, YA, YB);
        VWAIT(0);                 // bank nb (issued a full superbody ago) landed
        STEP2(XA, XB); DSRD2(nb, 0, XA, XB);
        STEP2(YA, YB); DSRD2(nb, 1, YA, YB);
        ISSUE16(rb, base);        // rows 8(j+2) into drained bank rb
        rb = nb;
        base += 8;
    }

    // superbody j=142 (steps 1136..1143): rb=0 (rows 1136-43); no more issue.
    STEP2(XA, XB); DSRD2(0, 2, XA, XB);
    STEP2(YA, YB); DSRD2(0, 3, YA, YB);
    STEP2(XA, XB); DSRD2(0, 4, XA, XB);
    STEP2(YA, YB); DSRD2(0, 5, YA, YB);
    STEP2(XA, XB); DSRD2(0, 6, XA, XB);
    STEP2(YA, YB); DSRD2(0, 7, YA, YB);
    VWAIT(0);                     // bank 1 (rows 1144-51) landed
    STEP2(XA, XB); DSRD2(1, 0, XA, XB);
    STEP2(YA, YB); DSRD2(1, 1, YA, YB);

    // tail: steps 1144..1149 from bank 1 (all landed)
    STEP2(XA, XB); DSRD2(1, 2, XA, XB);
    STEP2(YA, YB); DSRD2(1, 3, YA, YB);
    STEP2(XA, XB); DSRD2(1, 4, XA, XB);
    STEP2(YA, YB); DSRD2(1, 5, YA, YB);
    STEP2(XA, XB);
    STEP2(YA, YB);

    // Lane 63's final step is k = 1023 + 2*63 = 1149 -> p15 = dtw[1023][1023].
    if (t == 63) {
        out[b0]     = 1.0f / (1.0f + pA15 * (1.0f / 2048.0f));
        out[b0 + 1] = 1.0f / (1.0f + pB15 * (1.0f / 2048.0f));
    }
}

// ---------------------------------------------------------------------------
extern "C" void kernel_launch(void* const* d_in, const int* in_sizes, int n_in,
                              void* d_out, int out_size, void* d_ws, size_t ws_size,
                              hipStream_t stream) {
    const float* s1 = (const float*)d_in[0];
    const float* s2 = (const float*)d_in[1];
    float* out = (float*)d_out;

    char* ws = (char*)d_ws;
    __hip_bfloat16* Abf  = (__hip_bfloat16*)(ws);                // 25165824 B
    __hip_bfloat16* Bbf  = (__hip_bfloat16*)(ws + 25165824);     // 25165824 B
    __hip_bfloat16* skew = (__hip_bfloat16*)(ws + 50331648);     // 16*1152*1024*2 = 37748736 B

    zero_holes_kernel<<<16 * 127, 256, 0, stream>>>((float4*)skew);
    norm_bf16_kernel<<<8192, 256, 0, stream>>>(s1, s2, Abf, Bbf);
    gemm_dist_kernel<<<16 * 64, 256, 0, stream>>>(Abf, Bbf, skew);
    dtw_dp_kernel<<<8, 64, 0, stream>>>(skew, out);
}